// Round 5
// baseline (336.671 us; speedup 1.0000x reference)
//
#include <hip/hip_runtime.h>

typedef __attribute__((ext_vector_type(8))) short bf16x8;
typedef __attribute__((ext_vector_type(4))) float f32x4;

static inline size_t align256(size_t x) { return (x + 255) & ~size_t(255); }

__device__ inline ushort f2bf(float f) {
  uint u = __float_as_uint(f);
  return (ushort)((u + 0x7FFFu + ((u >> 16) & 1u)) >> 16);  // RNE
}
__device__ inline float bf2f(ushort h) { return __uint_as_float(((uint)h) << 16); }

#define BW_SHIFT 8            // 256 nodes per bucket
#define NBUCK_MAX 512
#define CHUNK 8192
#define PH2_CAP 6144          // max staged edges per bucket (48 KB LDS)
#define CT_SHIFT 13           // col-tile = 8192 source nodes (4 MB of y12)
#define NCT 16                // bins per node

// ---------------- CSR build: two-phase binned counting sort ----------------

__global__ __launch_bounds__(256) void bucket_hist(const int* __restrict__ row,
                                                   int* __restrict__ bcnt, int E) {
  __shared__ int h[NBUCK_MAX];
  for (int i = threadIdx.x; i < NBUCK_MAX; i += 256) h[i] = 0;
  __syncthreads();
  for (int i = blockIdx.x * 256 + threadIdx.x; i < E; i += gridDim.x * 256)
    atomicAdd(&h[row[i] >> BW_SHIFT], 1);
  __syncthreads();
  for (int i = threadIdx.x; i < NBUCK_MAX; i += 256)
    if (h[i]) atomicAdd(&bcnt[i], h[i]);
}

__global__ __launch_bounds__(NBUCK_MAX) void bucket_scan(const int* __restrict__ bcnt,
                                                         int* __restrict__ boff,
                                                         int* __restrict__ gcur,
                                                         int* __restrict__ offp,
                                                         int E, int n) {
  __shared__ int sh[NBUCK_MAX];
  int t = threadIdx.x;
  int v = bcnt[t];
  sh[t] = v;
  __syncthreads();
  for (int o = 1; o < NBUCK_MAX; o <<= 1) {
    int a = (t >= o) ? sh[t - o] : 0;
    __syncthreads();
    sh[t] += a;
    __syncthreads();
  }
  int excl = sh[t] - v;
  boff[t] = excl;
  gcur[t] = excl;
  if (t == NBUCK_MAX - 1) boff[NBUCK_MAX] = E;
  if (t == 0) offp[n] = E;
}

__global__ __launch_bounds__(256) void bin_scatter(const int* __restrict__ row,
                                                   const int* __restrict__ col,
                                                   const float* __restrict__ w,
                                                   int* __restrict__ gcur,
                                                   int2* __restrict__ es_tmp, int E) {
  __shared__ int lh[NBUCK_MAX];
  __shared__ int lbase[NBUCK_MAX];
  int c0 = blockIdx.x * CHUNK;
  int c1 = min(c0 + CHUNK, E);
  for (int i = threadIdx.x; i < NBUCK_MAX; i += 256) lh[i] = 0;
  __syncthreads();
  for (int i = c0 + threadIdx.x; i < c1; i += 256)
    atomicAdd(&lh[row[i] >> BW_SHIFT], 1);
  __syncthreads();
  for (int i = threadIdx.x; i < NBUCK_MAX; i += 256) {
    int c = lh[i];
    lbase[i] = c ? atomicAdd(&gcur[i], c) : 0;
    lh[i] = 0;
  }
  __syncthreads();
  for (int i = c0 + threadIdx.x; i < c1; i += 256) {
    int r = row[i];
    int b = r >> BW_SHIFT;
    int pos = lbase[b] + atomicAdd(&lh[b], 1);
    es_tmp[pos] = make_int2(((r & 255) << 17) | col[i], __float_as_int(w[i]));
  }
}

// (d) per-bucket sort by (node, col-tile): LDS stage + 4096-bin hist/scan.
// Sorting each node's list by coarse col-tile makes all concurrent SpMM waves
// sweep the source table in the same order -> gather reuse clusters in L2/L3.
__global__ __launch_bounds__(256) void bucket_sort(const int2* __restrict__ es_tmp,
                                                   const int* __restrict__ boff,
                                                   int2* __restrict__ es,
                                                   int* __restrict__ offp, int n) {
  __shared__ int2 ebuf[PH2_CAP];       // 48 KB
  __shared__ int lh[256 * NCT];        // 16 KB
  __shared__ int tsum[256];
  int b = blockIdx.x;
  int base = boff[b], cnt = boff[b + 1] - base;
  int t = threadIdx.x;
  bool fits = (cnt <= PH2_CAP);
  for (int i = t; i < 256 * NCT; i += 256) lh[i] = 0;
  __syncthreads();
  for (int i = t; i < cnt; i += 256) {
    int2 ed = es_tmp[base + i];
    if (fits) ebuf[i] = ed;
    int key = ((ed.x >> 17) & 255) * NCT + ((ed.x & 0x1FFFF) >> CT_SHIFT);
    atomicAdd(&lh[key], 1);
  }
  __syncthreads();
  // scan over 4096 bins: thread t owns bins [t*NCT, (t+1)*NCT) = node t's bins
  int loc[NCT];
  int s = 0;
#pragma unroll
  for (int j = 0; j < NCT; ++j) { loc[j] = s; s += lh[t * NCT + j]; }
  tsum[t] = s;
  __syncthreads();
  int v = tsum[t];
  for (int o = 1; o < 256; o <<= 1) {
    int a = (t >= o) ? tsum[t - o] : 0;
    __syncthreads();
    tsum[t] += a;
    __syncthreads();
  }
  int chunk_excl = tsum[t] - v;        // edges of nodes < this node in bucket
  int node = (b << BW_SHIFT) + t;
  if (node < n) offp[node] = base + chunk_excl;
#pragma unroll
  for (int j = 0; j < NCT; ++j) lh[t * NCT + j] = chunk_excl + loc[j];
  __syncthreads();
  for (int i = t; i < cnt; i += 256) {
    int2 ed = fits ? ebuf[i] : es_tmp[base + i];
    int key = ((ed.x >> 17) & 255) * NCT + ((ed.x & 0x1FFFF) >> CT_SHIFT);
    int pos = base + atomicAdd(&lh[key], 1);
    es[pos] = make_int2(ed.x & 0x1FFFF, ed.y);
  }
}

// ---------------- W transpose + bf16 convert ----------------

__global__ __launch_bounds__(256) void prep_wt_kernel(const float* __restrict__ W0,
                                                      const float* __restrict__ W1,
                                                      const float* __restrict__ W2,
                                                      ushort* __restrict__ Wt) {
  int i = blockIdx.x * 256 + threadIdx.x;
  if (i >= 3 * 16384) return;
  int mat = i >> 14, r = i & 16383;
  int k = r >> 7, c = r & 127;
  const float* W = (mat == 0) ? W0 : (mat == 1) ? W1 : W2;
  Wt[mat * 16384 + c * 128 + k] = f2bf(W[k * 128 + c]);
}

// ---------------- fused 3x GEMM via MFMA (swapped operands) ----------------

__global__ __launch_bounds__(256) void gemm3_kernel(
    const float* __restrict__ x, const ushort* __restrict__ Wt,
    const float* __restrict__ b0, const float* __restrict__ b1,
    const float* __restrict__ b2,
    float* __restrict__ out0,      // stride 384 (d_out col 0..127)
    ushort* __restrict__ y12,      // bf16 co-located y1|y2, stride 256
    int n) {
  int w = threadIdx.x >> 6;
  int l = threadIdx.x & 63;
  int lr = l & 15;
  int lg = l >> 4;
  int rows0 = blockIdx.x * 256 + w * 64;

  bf16x8 xf[4][4];
#pragma unroll
  for (int rt = 0; rt < 4; ++rt) {
    int row = rows0 + rt * 16 + lr;
    bool ok = row < n;
    const float* base = x + (size_t)row * 128;
#pragma unroll
    for (int kc = 0; kc < 4; ++kc) {
      float4 a = ok ? *(const float4*)(base + kc * 32 + lg * 8) : make_float4(0, 0, 0, 0);
      float4 c = ok ? *(const float4*)(base + kc * 32 + lg * 8 + 4) : make_float4(0, 0, 0, 0);
      bf16x8 f;
      f[0] = (short)f2bf(a.x); f[1] = (short)f2bf(a.y);
      f[2] = (short)f2bf(a.z); f[3] = (short)f2bf(a.w);
      f[4] = (short)f2bf(c.x); f[5] = (short)f2bf(c.y);
      f[6] = (short)f2bf(c.z); f[7] = (short)f2bf(c.w);
      xf[rt][kc] = f;
    }
  }

  for (int mat = 0; mat < 3; ++mat) {
    const ushort* Wm = Wt + mat * 16384;
    const float* bias = (mat == 0) ? b0 : (mat == 1) ? b1 : b2;
#pragma unroll 1
    for (int ct = 0; ct < 8; ++ct) {
      bf16x8 wf[4];
#pragma unroll
      for (int kc = 0; kc < 4; ++kc)
        wf[kc] = *(const bf16x8*)(Wm + (ct * 16 + lr) * 128 + kc * 32 + lg * 8);
      float4 bb = *(const float4*)(bias + ct * 16 + lg * 4);
      f32x4 acc[4];
#pragma unroll
      for (int rt = 0; rt < 4; ++rt) {
        acc[rt][0] = bb.x; acc[rt][1] = bb.y; acc[rt][2] = bb.z; acc[rt][3] = bb.w;
      }
#pragma unroll
      for (int kc = 0; kc < 4; ++kc)
#pragma unroll
        for (int rt = 0; rt < 4; ++rt)
          acc[rt] = __builtin_amdgcn_mfma_f32_16x16x32_bf16(wf[kc], xf[rt][kc], acc[rt], 0, 0, 0);
#pragma unroll
      for (int rt = 0; rt < 4; ++rt) {
        int row = rows0 + rt * 16 + lr;
        if (row >= n) continue;
        int col = ct * 16 + lg * 4;
        if (mat == 0) {
          *(f32x4*)(out0 + (size_t)row * 384 + col) = acc[rt];
        } else {
          ushort4 h;
          h.x = f2bf(acc[rt][0]); h.y = f2bf(acc[rt][1]);
          h.z = f2bf(acc[rt][2]); h.w = f2bf(acc[rt][3]);
          ushort* Y = y12 + (size_t)row * 256 + ((mat == 2) ? 128 : 0);
          *(ushort4*)(Y + col) = h;
        }
      }
    }
  }
}

// ---------------- SpMM (CSR, wave per node) ----------------

__global__ __launch_bounds__(256) void spmm_dual_kernel(
    const ushort* __restrict__ y12,
    float* __restrict__ o1,        // d_out + 128, stride 384
    ushort* __restrict__ z2,       // bf16, stride 128
    const int* __restrict__ off, const int2* __restrict__ es, int n) {
  int node = blockIdx.x * 4 + (threadIdx.x >> 6);
  if (node >= n) return;
  int l = threadIdx.x & 63;
  int s = off[node], e = off[node + 1];
  float a0 = 0.f, a1 = 0.f, c0 = 0.f, c1 = 0.f;
  int i = s;
  for (; i + 4 <= e; i += 4) {
    int2 ed[4];
    ed[0] = es[i]; ed[1] = es[i + 1]; ed[2] = es[i + 2]; ed[3] = es[i + 3];
    uint u1[4], u2[4];
#pragma unroll
    for (int j = 0; j < 4; ++j) {
      const ushort* base = y12 + (size_t)ed[j].x * 256;
      u1[j] = *(const uint*)(base + 2 * l);
      u2[j] = *(const uint*)(base + 128 + 2 * l);
    }
#pragma unroll
    for (int j = 0; j < 4; ++j) {
      float w = __int_as_float(ed[j].y);
      a0 += w * bf2f((ushort)u1[j]); a1 += w * bf2f((ushort)(u1[j] >> 16));
      c0 += w * bf2f((ushort)u2[j]); c1 += w * bf2f((ushort)(u2[j] >> 16));
    }
  }
  for (; i < e; ++i) {
    int2 e0 = es[i];
    float w = __int_as_float(e0.y);
    const ushort* base = y12 + (size_t)e0.x * 256;
    uint u1 = *(const uint*)(base + 2 * l);
    uint u2 = *(const uint*)(base + 128 + 2 * l);
    a0 += w * bf2f((ushort)u1); a1 += w * bf2f((ushort)(u1 >> 16));
    c0 += w * bf2f((ushort)u2); c1 += w * bf2f((ushort)(u2 >> 16));
  }
  *(float2*)(o1 + (size_t)node * 384 + 2 * l) = make_float2(a0, a1);
  uint z = (uint)f2bf(c0) | ((uint)f2bf(c1) << 16);
  *(uint*)(z2 + (size_t)node * 128 + 2 * l) = z;
}

__global__ __launch_bounds__(256) void spmm_single_kernel(
    const ushort* __restrict__ z2,
    float* __restrict__ o2,        // d_out + 256, stride 384
    const int* __restrict__ off, const int2* __restrict__ es, int n) {
  int node = blockIdx.x * 4 + (threadIdx.x >> 6);
  if (node >= n) return;
  int l = threadIdx.x & 63;
  int s = off[node], e = off[node + 1];
  float a0 = 0.f, a1 = 0.f;
  int i = s;
  for (; i + 4 <= e; i += 4) {
    int2 ed[4];
    ed[0] = es[i]; ed[1] = es[i + 1]; ed[2] = es[i + 2]; ed[3] = es[i + 3];
    uint u[4];
#pragma unroll
    for (int j = 0; j < 4; ++j)
      u[j] = *(const uint*)(z2 + (size_t)ed[j].x * 128 + 2 * l);
#pragma unroll
    for (int j = 0; j < 4; ++j) {
      float w = __int_as_float(ed[j].y);
      a0 += w * bf2f((ushort)u[j]); a1 += w * bf2f((ushort)(u[j] >> 16));
    }
  }
  for (; i < e; ++i) {
    int2 e0 = es[i];
    float w = __int_as_float(e0.y);
    uint u = *(const uint*)(z2 + (size_t)e0.x * 128 + 2 * l);
    a0 += w * bf2f((ushort)u); a1 += w * bf2f((ushort)(u >> 16));
  }
  *(float2*)(o2 + (size_t)node * 384 + 2 * l) = make_float2(a0, a1);
}

// ---------------- launch ----------------

extern "C" void kernel_launch(void* const* d_in, const int* in_sizes, int n_in,
                              void* d_out, int out_size, void* d_ws, size_t ws_size,
                              hipStream_t stream) {
  const float* x   = (const float*)d_in[0];
  const int*   row = (const int*)d_in[1];
  const int*   col = (const int*)d_in[2];
  const float* ew  = (const float*)d_in[3];
  const float* W0  = (const float*)d_in[4];
  const float* b0  = (const float*)d_in[5];
  const float* W1  = (const float*)d_in[6];
  const float* b1  = (const float*)d_in[7];
  const float* W2  = (const float*)d_in[8];
  const float* b2  = (const float*)d_in[9];
  float* out = (float*)d_out;

  int n = in_sizes[0] / 128;
  int E = in_sizes[1];

  char* p = (char*)d_ws;
  size_t o = 0;
  ushort* y12 = (ushort*)(p + o); o = align256(o + (size_t)n * 256 * 2);
  ushort* z2  = (ushort*)(p + o); o = align256(o + (size_t)n * 128 * 2);
  ushort* Wt  = (ushort*)(p + o); o = align256(o + (size_t)3 * 16384 * 2);
  int* bcnt   = (int*)(p + o);    o = align256(o + (size_t)NBUCK_MAX * 4);
  int* boff   = (int*)(p + o);    o = align256(o + (size_t)(NBUCK_MAX + 1) * 4);
  int* gcur   = (int*)(p + o);    o = align256(o + (size_t)NBUCK_MAX * 4);
  int* offp   = (int*)(p + o);    o = align256(o + ((size_t)n + 1) * 4);
  int2* es_t  = (int2*)(p + o);   o = align256(o + (size_t)E * 8);
  int2* es    = (int2*)(p + o);   o = align256(o + (size_t)E * 8);
  (void)ws_size; (void)n_in; (void)out_size;

  int nbuck = (n + 255) >> 8;

  // CSR build (binned counting sort; final order = (node, col-tile))
  hipMemsetAsync(bcnt, 0, (size_t)NBUCK_MAX * 4, stream);
  bucket_hist<<<1024, 256, 0, stream>>>(row, bcnt, E);
  bucket_scan<<<1, NBUCK_MAX, 0, stream>>>(bcnt, boff, gcur, offp, E, n);
  bin_scatter<<<(E + CHUNK - 1) / CHUNK, 256, 0, stream>>>(row, col, ew, gcur, es_t, E);
  bucket_sort<<<nbuck, 256, 0, stream>>>(es_t, boff, es, offp, n);

  // Weights -> bf16 transposed
  prep_wt_kernel<<<192, 256, 0, stream>>>(W0, W1, W2, Wt);

  // Fused GEMMs: out0 fp32, y12 bf16
  gemm3_kernel<<<(n + 255) / 256, 256, 0, stream>>>(x, Wt, b0, b1, b2,
                                                    out, y12, n);

  // x1 -> out[:,128:256], z2 (bf16) -> ws
  spmm_dual_kernel<<<(n + 3) / 4, 256, 0, stream>>>(y12, out + 128, z2,
                                                    offp, es, n);
  // x2 = A*z2 -> out[:,256:384]
  spmm_single_kernel<<<(n + 3) / 4, 256, 0, stream>>>(z2, out + 256,
                                                      offp, es, n);
}